// Round 3
// baseline (174.824 us; speedup 1.0000x reference)
//
#include <hip/hip_runtime.h>

constexpr int POOL  = 7;
constexpr int GRIDS = 2;
constexpr float SCALE = 0.0625f;
constexpr int C = 490, H = 100, W = 100;
constexpr int C_OUT = 10, HALF = 5;          // process c_out and c_out+5 per thread
constexpr int PLANE = H * W;
constexpr int CH_SPLIT_OFF = HALF * POOL * POOL * PLANE;  // 5*49*10000 = 2,450,000

__global__ __launch_bounds__(256) void psroi_align_kernel(
    const float* __restrict__ x, const float* __restrict__ rois,
    float* __restrict__ out, int K)
{
    int idx = blockIdx.x * blockDim.x + threadIdx.x;
    int total = K * HALF * POOL * POOL;
    if (idx >= total) return;

    int pw = idx % POOL;
    int t  = idx / POOL;
    int ph = t % POOL;
    t /= POOL;
    int c_out = t % HALF;
    int k     = t / HALF;

    const float* roi = rois + k * 5;
    int   b   = (int)roi[0];
    float rx1 = roi[1] * SCALE - 0.5f;
    float ry1 = roi[2] * SCALE - 0.5f;
    float rx2 = roi[3] * SCALE - 0.5f;
    float ry2 = roi[4] * SCALE - 0.5f;
    float bsh = (ry2 - ry1) * (1.0f / POOL);
    float bsw = (rx2 - rx1) * (1.0f / POOL);

    int c_in  = (c_out * POOL + ph) * POOL + pw;
    int off0  = (b * C + c_in) * PLANE;      // max ~19.6M, fits int

    // ---- per-axis pieces, branch-free ----
    int   rowlo[GRIDS], rowhi[GRIDS];
    float wyl[GRIDS], wyh[GRIDS];
    bool  vy[GRIDS];
    int   xlo[GRIDS], xhi[GRIDS];
    float wxl[GRIDS], wxh[GRIDS];
    bool  vx[GRIDS];

#pragma unroll
    for (int g = 0; g < GRIDS; ++g) {
        float yy = ry1 + ((float)ph + ((float)g + 0.5f) * (1.0f / GRIDS)) * bsh;
        vy[g] = (yy >= -1.0f) && (yy <= (float)H);
        float yc = fmaxf(yy, 0.0f);
        int lo = min((int)yc, H - 1);
        rowlo[g] = lo * W;
        rowhi[g] = min(lo + 1, H - 1) * W;
        float fy = (lo >= H - 1) ? 0.0f : (yc - (float)lo);
        wyl[g] = 1.0f - fy;
        wyh[g] = fy;

        float xxv = rx1 + ((float)pw + ((float)g + 0.5f) * (1.0f / GRIDS)) * bsw;
        vx[g] = (xxv >= -1.0f) && (xxv <= (float)W);
        float xc = fmaxf(xxv, 0.0f);
        int lo2 = min((int)xc, W - 1);
        xlo[g] = lo2;
        xhi[g] = min(lo2 + 1, W - 1);
        float fx = (lo2 >= W - 1) ? 0.0f : (xc - (float)lo2);
        wxl[g] = 1.0f - fx;
        wxh[g] = fx;
    }

    // ---- 16 shared offsets; 32 loads via two uniform bases ----
    const float* __restrict__ xb = x + CH_SPLIT_OFF;   // wave-uniform second base
    int   off[16];
#pragma unroll
    for (int gy = 0; gy < GRIDS; ++gy) {
#pragma unroll
        for (int gx = 0; gx < GRIDS; ++gx) {
            int p = (gy * GRIDS + gx) * 4;
            off[p + 0] = off0 + rowlo[gy] + xlo[gx];
            off[p + 1] = off0 + rowlo[gy] + xhi[gx];
            off[p + 2] = off0 + rowhi[gy] + xlo[gx];
            off[p + 3] = off0 + rowhi[gy] + xhi[gx];
        }
    }

    float va[16], vb[16];
#pragma unroll
    for (int p = 0; p < 16; ++p) va[p] = x[off[p]];
#pragma unroll
    for (int p = 0; p < 16; ++p) vb[p] = xb[off[p]];

    // ---- weighted reduction (weights shared by both channels) ----
    float accA = 0.0f, accB = 0.0f;
#pragma unroll
    for (int gy = 0; gy < GRIDS; ++gy) {
#pragma unroll
        for (int gx = 0; gx < GRIDS; ++gx) {
            int p = (gy * GRIDS + gx) * 4;
            float w  = (vy[gy] && vx[gx]) ? 0.25f : 0.0f;
            float a0 = wyl[gy] * wxl[gx] * w;
            float a1 = wyl[gy] * wxh[gx] * w;
            float a2 = wyh[gy] * wxl[gx] * w;
            float a3 = wyh[gy] * wxh[gx] * w;
            accA += a0 * va[p+0] + a1 * va[p+1] + a2 * va[p+2] + a3 * va[p+3];
            accB += a0 * vb[p+0] + a1 * vb[p+1] + a2 * vb[p+2] + a3 * vb[p+3];
        }
    }

    int outA = ((k * C_OUT + c_out) * POOL + ph) * POOL + pw;
    out[outA] = accA;
    out[outA + HALF * POOL * POOL] = accB;
}

extern "C" void kernel_launch(void* const* d_in, const int* in_sizes, int n_in,
                              void* d_out, int out_size, void* d_ws, size_t ws_size,
                              hipStream_t stream) {
    const float* x    = (const float*)d_in[0];
    const float* rois = (const float*)d_in[1];
    float* out = (float*)d_out;

    int K = in_sizes[1] / 5;                  // 2048
    int total = K * HALF * POOL * POOL;       // half the outputs; each thread does 2
    int threads = 256;
    int blocks = (total + threads - 1) / threads;
    psroi_align_kernel<<<blocks, threads, 0, stream>>>(x, rois, out, K);
}

// Round 4
// 139.771 us; speedup vs baseline: 1.2508x; 1.2508x over previous
//
#include <hip/hip_runtime.h>

constexpr int POOL  = 7;
constexpr int GRIDS = 2;
constexpr float SCALE = 0.0625f;
constexpr int C = 490, H = 100, W = 100;
constexpr int PLANE = H * W;

// Compute kernel, channel-major: block = (c_in, k-chunk of 256), lane = k.
// All k-chunks of one c_in share blockIdx%8 -> same XCD -> plane-set (4 imgs
// x 40KB = 160KB) is fetched into that XCD's L2 once and reused by all 2048
// ROIs. DIRECT=false: write ws[c_in*K + k] (coalesced); DIRECT=true: write
// out[k*C + c_in] (scattered fallback when ws is too small).
template<bool DIRECT>
__global__ __launch_bounds__(256) void psroi_cmajor_kernel(
    const float* __restrict__ x, const float* __restrict__ rois,
    float* __restrict__ dst, int K, int numKC)
{
    int bid  = blockIdx.x;
    int c_lo = bid & 7;
    int t    = bid >> 3;
    int kc   = t % numKC;
    int c_hi = t / numKC;
    int c_in = c_hi * 8 + c_lo;
    if (c_in >= C) return;
    int k = kc * 256 + (int)threadIdx.x;
    if (k >= K) return;

    int ph = (c_in / POOL) % POOL;
    int pw = c_in % POOL;

    const float* roi = rois + k * 5;
    int   img = (int)roi[0];
    float rx1 = roi[1] * SCALE - 0.5f;
    float ry1 = roi[2] * SCALE - 0.5f;
    float rx2 = roi[3] * SCALE - 0.5f;
    float ry2 = roi[4] * SCALE - 0.5f;
    float bsh = (ry2 - ry1) * (1.0f / POOL);
    float bsw = (rx2 - rx1) * (1.0f / POOL);

    int off0 = (img * C + c_in) * PLANE;   // < 19.6M, fits int

    // ---- per-axis pieces, branch-free ----
    int   rowlo[GRIDS], rowhi[GRIDS];
    float wyl[GRIDS], wyh[GRIDS];
    bool  vy[GRIDS];
    int   xlo[GRIDS], xhi[GRIDS];
    float wxl[GRIDS], wxh[GRIDS];
    bool  vx[GRIDS];

#pragma unroll
    for (int g = 0; g < GRIDS; ++g) {
        float yy = ry1 + ((float)ph + ((float)g + 0.5f) * (1.0f / GRIDS)) * bsh;
        vy[g] = (yy >= -1.0f) && (yy <= (float)H);
        float yc = fmaxf(yy, 0.0f);
        int lo = min((int)yc, H - 1);
        rowlo[g] = lo * W;
        rowhi[g] = min(lo + 1, H - 1) * W;
        float fy = (lo >= H - 1) ? 0.0f : (yc - (float)lo);
        wyl[g] = 1.0f - fy;
        wyh[g] = fy;

        float xxv = rx1 + ((float)pw + ((float)g + 0.5f) * (1.0f / GRIDS)) * bsw;
        vx[g] = (xxv >= -1.0f) && (xxv <= (float)W);
        float xc = fmaxf(xxv, 0.0f);
        int lo2 = min((int)xc, W - 1);
        xlo[g] = lo2;
        xhi[g] = min(lo2 + 1, W - 1);
        float fx = (lo2 >= W - 1) ? 0.0f : (xc - (float)lo2);
        wxl[g] = 1.0f - fx;
        wxh[g] = fx;
    }

    // ---- all 16 loads issued unconditionally, weight-zero when invalid ----
    float v[16];
#pragma unroll
    for (int gy = 0; gy < GRIDS; ++gy) {
#pragma unroll
        for (int gx = 0; gx < GRIDS; ++gx) {
            int p = (gy * GRIDS + gx) * 4;
            v[p + 0] = x[off0 + rowlo[gy] + xlo[gx]];
            v[p + 1] = x[off0 + rowlo[gy] + xhi[gx]];
            v[p + 2] = x[off0 + rowhi[gy] + xlo[gx]];
            v[p + 3] = x[off0 + rowhi[gy] + xhi[gx]];
        }
    }

    float acc = 0.0f;
#pragma unroll
    for (int gy = 0; gy < GRIDS; ++gy) {
#pragma unroll
        for (int gx = 0; gx < GRIDS; ++gx) {
            int p = (gy * GRIDS + gx) * 4;
            float w = (vy[gy] && vx[gx]) ? 0.25f : 0.0f;
            acc += w * (wyl[gy] * (wxl[gx] * v[p+0] + wxh[gx] * v[p+1])
                      + wyh[gy] * (wxl[gx] * v[p+2] + wxh[gx] * v[p+3]));
        }
    }

    if (DIRECT) {
        dst[k * C + c_in] = acc;        // output layout (k, c_in)
    } else {
        dst[c_in * K + k] = acc;        // coalesced scratch, transposed later
    }
}

// ws[c_in*K + k] -> out[k*C + c_in]; lane-fast over c_in => coalesced stores.
__global__ __launch_bounds__(256) void transpose_kernel(
    const float* __restrict__ ws, float* __restrict__ out, int K, int total)
{
    int i = blockIdx.x * 256 + (int)threadIdx.x;
    if (i >= total) return;
    int c = i % C;
    int k = i / C;
    out[i] = ws[c * K + k];
}

extern "C" void kernel_launch(void* const* d_in, const int* in_sizes, int n_in,
                              void* d_out, int out_size, void* d_ws, size_t ws_size,
                              hipStream_t stream) {
    const float* x    = (const float*)d_in[0];
    const float* rois = (const float*)d_in[1];
    float* out = (float*)d_out;

    int K = in_sizes[1] / 5;                  // 2048
    int numKC = (K + 255) / 256;
    int cGroups = (C + 7) / 8;                // 62
    int blocks = cGroups * numKC * 8;

    bool use_ws = ws_size >= (size_t)C * (size_t)K * sizeof(float);
    if (use_ws) {
        float* ws = (float*)d_ws;
        psroi_cmajor_kernel<false><<<blocks, 256, 0, stream>>>(x, rois, ws, K, numKC);
        int total = K * C;
        transpose_kernel<<<(total + 255) / 256, 256, 0, stream>>>(ws, out, K, total);
    } else {
        psroi_cmajor_kernel<true><<<blocks, 256, 0, stream>>>(x, rois, out, K, numKC);
    }
}